// Round 11
// baseline (391.461 us; speedup 1.0000x reference)
//
#include <hip/hip_runtime.h>
#include <math.h>

// ---------------- constants (shapes fixed by the reference) ----------------
#define IN_CH   256
#define HC      256   // H*C
#define H_HEADS 4
#define NEG_SLOPE 0.2f
#define LOG2E   1.44269504088896f
#define MINIT   -3.0e38f  // finite "-inf": exp2(-INF - MINIT) == 0 exactly

typedef __attribute__((ext_vector_type(8))) short short8;
typedef __attribute__((ext_vector_type(4))) float float4v;
typedef __attribute__((ext_vector_type(2))) unsigned uint2v;

// ---------------- helpers ----------------
__device__ __forceinline__ float bf2f(unsigned short b) {
    return __uint_as_float(((unsigned)b) << 16);
}
__device__ __forceinline__ float blo(unsigned u) {   // low bf16 of a dword
    return __uint_as_float(u << 16);
}
__device__ __forceinline__ float bhi(unsigned u) {   // high bf16 of a dword
    return __uint_as_float(u & 0xffff0000u);
}
__device__ __forceinline__ unsigned short f2bf(float f) {
    unsigned u = __float_as_uint(f);
    u += 0x7fffu + ((u >> 16) & 1u);    // round-to-nearest-even
    return (unsigned short)(u >> 16);
}
__device__ __forceinline__ float lrelu(float a) {
    return a >= 0.f ? a : NEG_SLOPE * a;
}
// base-2 exp: single v_exp_f32 (natively 2^x on gfx950).
__device__ __forceinline__ float fexp2(float a) {
    return __builtin_amdgcn_exp2f(a);
}

// ---------------- kernels ----------------

// W (fp32, [256k x 256c] row-major) -> transposed bf16 (wt[c][k])
__global__ void prep_w(const float* __restrict__ w,
                       unsigned short* __restrict__ wt) {
    int idx = blockIdx.x * 256 + threadIdx.x;   // 65536 total
    int k = idx >> 8, c = idx & 255;
    wt[(size_t)c * 256 + k] = f2bf(w[idx]);
}

// xh = x @ W. Block = 16 rows x 256 cols (4 waves = 4 heads).
// OUTPUT IN CHANNEL-PLANE LAYOUT: xh_pl[plane][node][32ch], plane = ch>>5.
// Each plane is N*64 B = 3.2 MB -> fits a single XCD's 4 MiB L2.
// Epilogue fuses node_attn (base-2 domain).
__global__ __launch_bounds__(256) void gemm_xh(const float* __restrict__ x,
                                               const unsigned short* __restrict__ wt,
                                               const float* __restrict__ att_s,
                                               const float* __restrict__ att_d,
                                               unsigned short* __restrict__ xh_pl,
                                               float* __restrict__ a_src,
                                               float* __restrict__ a_dst, int N) {
    __shared__ __attribute__((aligned(16))) unsigned char lds_a[16384];
    int tid  = threadIdx.x;
    int wave = tid >> 6;            // == head index
    int lane = tid & 63;
    int quad = lane >> 4;
    int l16  = lane & 15;
    int rb   = blockIdx.x * 16;

    // ---- stage A-tile: 512 chunks x 8 floats -> hi/lo short8 slots ----
#pragma unroll
    for (int pass = 0; pass < 2; ++pass) {
        int s  = pass * 256 + tid;              // 0..511
        int kc = s >> 4;                        // 16-B chunk index (k/8)
        int m  = s & 15;                        // row within tile
        int grow = rb + m; if (grow >= N) grow = N - 1;
        const float* gp = x + (size_t)grow * IN_CH + kc * 8;
        float4v f0 = *(const float4v*)gp;
        float4v f1 = *(const float4v*)(gp + 4);
        short8 hi, lo;
#pragma unroll
        for (int j = 0; j < 4; ++j) {
            unsigned short h0 = f2bf(f0[j]);
            hi[j] = (short)h0;
            lo[j] = (short)f2bf(f0[j] - bf2f(h0));
            unsigned short h1 = f2bf(f1[j]);
            hi[4 + j] = (short)h1;
            lo[4 + j] = (short)f2bf(f1[j] - bf2f(h1));
        }
        *(short8*)(lds_a + (size_t)s * 16) = hi;
        *(short8*)(lds_a + 8192 + (size_t)s * 16) = lo;
    }
    __syncthreads();

    // ---- K-loop: 8 x { 2 ds_read_b128 + 4 x (1 B-load + 2 MFMA) } ----
    float4v acc[4] = {};
    const unsigned short* wt_base = wt + ((size_t)wave * 64 + l16) * IN_CH;
#pragma unroll
    for (int k0 = 0; k0 < 8; ++k0) {
        int kc   = k0 * 4 + quad;
        int slot = kc * 16 + l16;
        short8 a_hi = *(const short8*)(lds_a + slot * 16);
        short8 a_lo = *(const short8*)(lds_a + 8192 + slot * 16);
#pragma unroll
        for (int ct = 0; ct < 4; ++ct) {
            short8 bh = *(const short8*)(wt_base + (size_t)ct * 16 * IN_CH
                                         + k0 * 32 + quad * 8);
            acc[ct] = __builtin_amdgcn_mfma_f32_16x16x32_bf16(a_lo, bh, acc[ct], 0, 0, 0);
            acc[ct] = __builtin_amdgcn_mfma_f32_16x16x32_bf16(a_hi, bh, acc[ct], 0, 0, 0);
        }
    }

    // ---- epilogue: plane-layout xh store + fused a_src/a_dst ----
    int cb = wave;
    float ps[4] = {0.f, 0.f, 0.f, 0.f};
    float pd[4] = {0.f, 0.f, 0.f, 0.f};
#pragma unroll
    for (int ct = 0; ct < 4; ++ct) {
        float as_c = att_s[cb * 64 + ct * 16 + l16] * LOG2E;
        float ad_c = att_d[cb * 64 + ct * 16 + l16] * LOG2E;
        int ch = cb * 64 + ct * 16 + l16;
        int pl = ch >> 5, wc = ch & 31;
#pragma unroll
        for (int r = 0; r < 4; ++r) {
            float v = acc[ct][r];
            int grow = rb + quad * 4 + r;
            if (grow < N)
                xh_pl[((size_t)pl * N + grow) * 32 + wc] = f2bf(v);
            ps[r] += v * as_c;
            pd[r] += v * ad_c;
        }
    }
#pragma unroll
    for (int off = 1; off < 16; off <<= 1) {
#pragma unroll
        for (int r = 0; r < 4; ++r) {
            ps[r] += __shfl_xor(ps[r], off);
            pd[r] += __shfl_xor(pd[r], off);
        }
    }
    if (l16 == 0) {
#pragma unroll
        for (int r = 0; r < 4; ++r) {
            int grow = rb + quad * 4 + r;
            if (grow < N) {
                a_src[(size_t)grow * 4 + cb] = ps[r];
                a_dst[(size_t)grow * 4 + cb] = pd[r];
            }
        }
    }
}

// degree histogram over dst
__global__ __launch_bounds__(256) void deg_count(const int* __restrict__ ei,
                                                 int* __restrict__ deg, int E) {
    int e = blockIdx.x * 256 + threadIdx.x;
    if (e >= E) return;
    atomicAdd(deg + ei[E + e], 1);
}

// ---- device-wide exclusive scan of deg[N] -> rowptr, cursor (2 phases) ----
__global__ __launch_bounds__(256) void scan_part(const int* __restrict__ deg,
                                                 int* __restrict__ part, int N) {
    int t = threadIdx.x;
    int base = blockIdx.x * 1024 + t * 4;
    int s = 0;
    if (base + 4 <= N) {
        int4 v = *(const int4*)(deg + base);
        s = v.x + v.y + v.z + v.w;
    } else {
#pragma unroll
        for (int j = 0; j < 4; ++j)
            if (base + j < N) s += deg[base + j];
    }
#pragma unroll
    for (int off = 1; off < 64; off <<= 1) s += __shfl_xor(s, off);
    __shared__ int ws[4];
    if ((t & 63) == 0) ws[t >> 6] = s;
    __syncthreads();
    if (t == 0) part[blockIdx.x] = ws[0] + ws[1] + ws[2] + ws[3];
}

__global__ __launch_bounds__(256) void scan_final(const int* __restrict__ deg,
                                                  const int* __restrict__ part,
                                                  int* __restrict__ rowptr,
                                                  int* __restrict__ cursor, int N) {
    __shared__ int sm[256];
    __shared__ int wsum[4];
    int t = threadIdx.x;
    int bacc = 0;
    for (int j = t; j < blockIdx.x; j += 256) bacc += part[j];
#pragma unroll
    for (int off = 1; off < 64; off <<= 1) bacc += __shfl_xor(bacc, off);
    if ((t & 63) == 0) wsum[t >> 6] = bacc;

    int base = blockIdx.x * 1024 + t * 4;
    int v0 = 0, v1 = 0, v2 = 0, v3 = 0;
    if (base + 4 <= N) {
        int4 v = *(const int4*)(deg + base);
        v0 = v.x; v1 = v.y; v2 = v.z; v3 = v.w;
    } else {
        if (base + 0 < N) v0 = deg[base + 0];
        if (base + 1 < N) v1 = deg[base + 1];
        if (base + 2 < N) v2 = deg[base + 2];
        if (base + 3 < N) v3 = deg[base + 3];
    }
    int s = v0 + v1 + v2 + v3;
    sm[t] = s;
    __syncthreads();
    for (int off = 1; off < 256; off <<= 1) {
        int tmp = (t >= off) ? sm[t - off] : 0;
        __syncthreads();
        sm[t] += tmp;
        __syncthreads();
    }
    int boff = wsum[0] + wsum[1] + wsum[2] + wsum[3];
    int run = boff + sm[t] - s;   // exclusive prefix for this thread
    int r0 = run, r1 = r0 + v0, r2 = r1 + v1, r3 = r2 + v2;
    if (base + 4 <= N) {
        *(int4*)(rowptr + base) = (int4){r0, r1, r2, r3};
        *(int4*)(cursor + base) = (int4){r0, r1, r2, r3};
    } else {
        if (base + 0 < N) { rowptr[base + 0] = r0; cursor[base + 0] = r0; }
        if (base + 1 < N) { rowptr[base + 1] = r1; cursor[base + 1] = r1; }
        if (base + 2 < N) { rowptr[base + 2] = r2; cursor[base + 2] = r2; }
        if (base + 3 < N) { rowptr[base + 3] = r3; cursor[base + 3] = r3; }
    }
}

// fill CSR: minimal scattered write -- ONE 4-B store per edge.
__global__ __launch_bounds__(256) void fill_csr(const int* __restrict__ ei,
                                                int* __restrict__ cursor,
                                                int* __restrict__ csr_off6, int E) {
    int e = blockIdx.x * 256 + threadIdx.x;
    if (e >= E) return;
    int s = ei[e], d = ei[E + e];
    int slot = atomicAdd(cursor + d, 1);
    csr_off6[slot] = s << 6;   // byte offset into one plane (64 B/row)
}

// softmax stats per (dst, head) + PER-EDGE WEIGHT MATERIALIZATION.
// Pass 1: exact online max/sum (al recomputed from L2-hot a_src/a_dst).
// Pass 2: p_soa[h][slot] = exp2(al - m) * inv -- the plane-independent
// edge weight, written ONCE here so gat_planes doesn't replicate the
// a_src gather + lrelu + exp2 across 8 planes (round 10: VALUBusy 96%).
// Writes are sequential per thread (slot-ordered).
__global__ __launch_bounds__(256) void softmax_stats(const int* __restrict__ csr_off6,
                                                     const float* __restrict__ a_src,
                                                     const float* __restrict__ a_dst,
                                                     const int* __restrict__ rowptr,
                                                     const int* __restrict__ deg,
                                                     float* __restrict__ pack,
                                                     float* __restrict__ p_soa,
                                                     int N, int E) {
    int d = blockIdx.x * 256 + threadIdx.x;
    int h = blockIdx.y;
    if (d >= N) return;
    int start = rowptr[d], cnt = deg[d];
    float adh = a_dst[(size_t)d * 4 + h];
    const int* offs = csr_off6 + start;
    float m = MINIT, l = 0.f;
    for (int i = 0; i < cnt; ++i) {
        int off = offs[i];                       // s<<6
        float al = lrelu(a_src[(off >> 4) + h] + adh);   // off>>4 == s*4
        float mn = fmaxf(m, al);
        l = l * fexp2(m - mn) + fexp2(al - mn);
        m = mn;
    }
    float inv = 1.f / (l + 1e-16f);
    pack[(size_t)d * 8 + h]     = m;
    pack[(size_t)d * 8 + 4 + h] = inv;
    float* pout = p_soa + (size_t)h * E + start;
    for (int i = 0; i < cnt; ++i) {
        int off = offs[i];
        float al = lrelu(a_src[(off >> 4) + h] + adh);
        pout[i] = fexp2(al - m) * inv;
    }
}

// Channel-plane weighted gather, weight-hoisted: per edge-instance just
// {seq off load, seq p load, dwordx2 x-gather, 4 unpack, 4 FMA} -- no
// exp2/lrelu/a_src in the loop, no final scale (p sums to 1).
// 8 lanes/dst x 4ch (dwordx2) -> 8 dsts per wave. plane = blockIdx&7
// (round-robin XCDs -> 3.2 MB plane L2-resident; round 10 measured
// FETCH at the 25.6 MB minimum). Pads: off->0 (hot line), p->0.
__global__ __launch_bounds__(256) void gat_planes(const int* __restrict__ csr_off6,
                                                  const float* __restrict__ p_soa,
                                                  const int* __restrict__ rowptr,
                                                  const int* __restrict__ deg,
                                                  const unsigned short* __restrict__ xh_pl,
                                                  float* __restrict__ out, int N, int E) {
    int tid = threadIdx.x;
    int g   = blockIdx.x & 7;            // plane -> XCD (round-robin heuristic)
    int db  = blockIdx.x >> 3;
    int grp = tid >> 3;                  // 32 dst-groups per block
    int l8  = tid & 7;
    int d   = db * 32 + grp;
    bool dv = d < N;
    int dc  = dv ? d : N - 1;
    int start = rowptr[dc];
    int cnt   = dv ? deg[dc] : 0;
    int h = g >> 1;                      // head covered by this plane

    // wave-max count across the 8 dst-groups in this wave
    int cw = cnt;
    cw = max(cw, __shfl_xor(cw, 8));
    cw = max(cw, __shfl_xor(cw, 16));
    cw = max(cw, __shfl_xor(cw, 32));

    const char* pb = (const char*)xh_pl + (size_t)g * N * 64;
    const float* ph = p_soa + (size_t)h * E + start;
    int lb = l8 * 8;

    float a0 = 0.f, a1 = 0.f, a2 = 0.f, a3 = 0.f;

#define POFF(i) (((i) < cnt) ? csr_off6[start + (i)] : 0)
#define PPV(i)  (((i) < cnt) ? ph[i] : 0.f)

    int   oE  = POFF(0), oO  = POFF(1);
    float pE  = PPV(0),  pO  = PPV(1);
    int   oE1 = POFF(2), oO1 = POFF(3);
    float pE1 = PPV(2),  pO1 = PPV(3);

#pragma unroll 2
    for (int i = 0; i < cw; i += 2) {
        uint2v xE = *(const uint2v*)(pb + (size_t)(unsigned)oE + lb);
        uint2v xO = *(const uint2v*)(pb + (size_t)(unsigned)oO + lb);
        int   oE2 = POFF(i + 4), oO2 = POFF(i + 5);
        float pE2 = PPV(i + 4),  pO2 = PPV(i + 5);

        a0 += pE * blo(xE[0]); a1 += pE * bhi(xE[0]);
        a2 += pE * blo(xE[1]); a3 += pE * bhi(xE[1]);
        a0 += pO * blo(xO[0]); a1 += pO * bhi(xO[0]);
        a2 += pO * blo(xO[1]); a3 += pO * bhi(xO[1]);

        oE = oE1; oO = oO1; oE1 = oE2; oO1 = oO2;
        pE = pE1; pO = pO1; pE1 = pE2; pO1 = pO2;
    }
#undef POFF
#undef PPV

    if (dv) {
        float4v o;
        o[0] = a0; o[1] = a1; o[2] = a2; o[3] = a3;
        *(float4v*)(out + (size_t)d * HC + g * 32 + l8 * 4) = o;
    }
}

// att[e,:] = exp2(lrelu(as+ad) - m[d]) * inv_l[d].
__global__ __launch_bounds__(256) void att_edge(const int* __restrict__ ei,
                                                const float* __restrict__ a_src,
                                                const float* __restrict__ a_dst,
                                                const float* __restrict__ pack,
                                                float* __restrict__ att_out, int E) {
    int e = blockIdx.x * 256 + threadIdx.x;
    if (e >= E) return;
    int s = ei[e], d = ei[E + e];
    float4v as = *(const float4v*)(a_src + (size_t)s * 4);
    float4v ad = *(const float4v*)(a_dst + (size_t)d * 4);
    float4v mm = *(const float4v*)(pack + (size_t)d * 8);
    float4v gg = *(const float4v*)(pack + (size_t)d * 8 + 4);
    float4v o;
#pragma unroll
    for (int h = 0; h < 4; ++h)
        o[h] = fexp2(lrelu(as[h] + ad[h]) - mm[h]) * gg[h];
    *(float4v*)(att_out + (size_t)e * 4) = o;
}

// ---------------- launcher ----------------
extern "C" void kernel_launch(void* const* d_in, const int* in_sizes, int n_in,
                              void* d_out, int out_size, void* d_ws, size_t ws_size,
                              hipStream_t stream) {
    const float* x     = (const float*)d_in[0];  // fp32 [N,256]
    const int*   ei    = (const int*)d_in[1];    // int32 [2,E]
    const float* W     = (const float*)d_in[2];  // fp32 [256,256]
    const float* att_s = (const float*)d_in[3];  // fp32 [4,64]
    const float* att_d = (const float*)d_in[4];  // fp32 [4,64]

    const int N = in_sizes[0] / IN_CH;   // 50000
    const int E = in_sizes[1] / 2;       // 800000

    char* ws = (char*)d_ws;
    size_t off = 0;
    unsigned short* xh_pl = (unsigned short*)(ws + off); off += (size_t)N * HC * 2;
    unsigned short* wt    = (unsigned short*)(ws + off); off += (size_t)IN_CH * HC * 2;
    float* a_src = (float*)(ws + off); off += (size_t)N * H_HEADS * 4;
    float* a_dst = (float*)(ws + off); off += (size_t)N * H_HEADS * 4;
    float* pack  = (float*)(ws + off); off += (size_t)N * 8 * 4;
    int* rowptr  = (int*)(ws + off); off += (size_t)N * 4;
    int* cursor  = (int*)(ws + off); off += (size_t)N * 4;
    int* csr_off6 = (int*)(ws + off); off += (size_t)E * 4;
    float* p_soa = (float*)(ws + off); off += (size_t)E * 4 * 4;  // SoA [4][E]
    int* part    = (int*)(ws + off); off += 1024 * 4;   // scan partials
    size_t zoff = off;  // zero-init region
    int* deg     = (int*)(ws + off); off += (size_t)N * 4;

    float* out     = (float*)d_out;            // [N, 256] fp32
    float* out_att = out + (size_t)N * HC;     // [E, 4]   fp32

    (void)hipMemsetAsync(ws + zoff, 0, off - zoff, stream);  // deg only

    const int NB  = (N + 1023) / 1024;         // scan blocks (49 for N=50000)
    const int NDB = (N + 31) / 32;             // dst-blocks per plane (1563)

    prep_w<<<256, 256, 0, stream>>>(W, wt);
    deg_count<<<(E + 255) / 256, 256, 0, stream>>>(ei, deg, E);
    gemm_xh<<<(N + 15) / 16, 256, 0, stream>>>(x, wt, att_s, att_d,
                                               xh_pl, a_src, a_dst, N);
    scan_part<<<NB, 256, 0, stream>>>(deg, part, N);
    scan_final<<<NB, 256, 0, stream>>>(deg, part, rowptr, cursor, N);
    fill_csr<<<(E + 255) / 256, 256, 0, stream>>>(ei, cursor, csr_off6, E);
    softmax_stats<<<dim3((N + 255) / 256, 4), 256, 0, stream>>>(csr_off6, a_src, a_dst,
                                                                rowptr, deg, pack,
                                                                p_soa, N, E);
    gat_planes<<<NDB * 8, 256, 0, stream>>>(csr_off6, p_soa, rowptr, deg,
                                            xh_pl, out, N, E);
    att_edge<<<(E + 255) / 256, 256, 0, stream>>>(ei, a_src, a_dst, pack,
                                                  out_att, E);
}

// Round 12
// 348.457 us; speedup vs baseline: 1.1234x; 1.1234x over previous
//
#include <hip/hip_runtime.h>
#include <math.h>

// ---------------- constants (shapes fixed by the reference) ----------------
#define IN_CH   256
#define HC      256   // H*C
#define H_HEADS 4
#define NEG_SLOPE 0.2f
#define LOG2E   1.44269504088896f
#define MINIT   -3.0e38f  // finite "-inf": exp2(-INF - MINIT) == 0 exactly

typedef __attribute__((ext_vector_type(8))) short short8;
typedef __attribute__((ext_vector_type(4))) float float4v;
typedef __attribute__((ext_vector_type(2))) unsigned uint2v;

// ---------------- helpers ----------------
__device__ __forceinline__ float bf2f(unsigned short b) {
    return __uint_as_float(((unsigned)b) << 16);
}
__device__ __forceinline__ float blo(unsigned u) {   // low bf16 of a dword
    return __uint_as_float(u << 16);
}
__device__ __forceinline__ float bhi(unsigned u) {   // high bf16 of a dword
    return __uint_as_float(u & 0xffff0000u);
}
__device__ __forceinline__ unsigned short f2bf(float f) {
    unsigned u = __float_as_uint(f);
    u += 0x7fffu + ((u >> 16) & 1u);    // round-to-nearest-even
    return (unsigned short)(u >> 16);
}
__device__ __forceinline__ float lrelu(float a) {
    return a >= 0.f ? a : NEG_SLOPE * a;
}
// base-2 exp: single v_exp_f32 (natively 2^x on gfx950).
__device__ __forceinline__ float fexp2(float a) {
    return __builtin_amdgcn_exp2f(a);
}

// ---------------- kernels ----------------

// W (fp32, [256k x 256c] row-major) -> transposed bf16 (wt[c][k])
__global__ void prep_w(const float* __restrict__ w,
                       unsigned short* __restrict__ wt) {
    int idx = blockIdx.x * 256 + threadIdx.x;   // 65536 total
    int k = idx >> 8, c = idx & 255;
    wt[(size_t)c * 256 + k] = f2bf(w[idx]);
}

// xh = x @ W. Block = 16 rows x 256 cols (4 waves = 4 heads).
// OUTPUT IN CHANNEL-PLANE LAYOUT: xh_pl[plane][node][32ch], plane = ch>>5.
// Each plane is N*64 B = 3.2 MB -> fits a single XCD's 4 MiB L2.
// Epilogue fuses node_attn (base-2 domain).
__global__ __launch_bounds__(256) void gemm_xh(const float* __restrict__ x,
                                               const unsigned short* __restrict__ wt,
                                               const float* __restrict__ att_s,
                                               const float* __restrict__ att_d,
                                               unsigned short* __restrict__ xh_pl,
                                               float* __restrict__ a_src,
                                               float* __restrict__ a_dst, int N) {
    __shared__ __attribute__((aligned(16))) unsigned char lds_a[16384];
    int tid  = threadIdx.x;
    int wave = tid >> 6;            // == head index
    int lane = tid & 63;
    int quad = lane >> 4;
    int l16  = lane & 15;
    int rb   = blockIdx.x * 16;

    // ---- stage A-tile: 512 chunks x 8 floats -> hi/lo short8 slots ----
#pragma unroll
    for (int pass = 0; pass < 2; ++pass) {
        int s  = pass * 256 + tid;              // 0..511
        int kc = s >> 4;                        // 16-B chunk index (k/8)
        int m  = s & 15;                        // row within tile
        int grow = rb + m; if (grow >= N) grow = N - 1;
        const float* gp = x + (size_t)grow * IN_CH + kc * 8;
        float4v f0 = *(const float4v*)gp;
        float4v f1 = *(const float4v*)(gp + 4);
        short8 hi, lo;
#pragma unroll
        for (int j = 0; j < 4; ++j) {
            unsigned short h0 = f2bf(f0[j]);
            hi[j] = (short)h0;
            lo[j] = (short)f2bf(f0[j] - bf2f(h0));
            unsigned short h1 = f2bf(f1[j]);
            hi[4 + j] = (short)h1;
            lo[4 + j] = (short)f2bf(f1[j] - bf2f(h1));
        }
        *(short8*)(lds_a + (size_t)s * 16) = hi;
        *(short8*)(lds_a + 8192 + (size_t)s * 16) = lo;
    }
    __syncthreads();

    // ---- K-loop: 8 x { 2 ds_read_b128 + 4 x (1 B-load + 2 MFMA) } ----
    float4v acc[4] = {};
    const unsigned short* wt_base = wt + ((size_t)wave * 64 + l16) * IN_CH;
#pragma unroll
    for (int k0 = 0; k0 < 8; ++k0) {
        int kc   = k0 * 4 + quad;
        int slot = kc * 16 + l16;
        short8 a_hi = *(const short8*)(lds_a + slot * 16);
        short8 a_lo = *(const short8*)(lds_a + 8192 + slot * 16);
#pragma unroll
        for (int ct = 0; ct < 4; ++ct) {
            short8 bh = *(const short8*)(wt_base + (size_t)ct * 16 * IN_CH
                                         + k0 * 32 + quad * 8);
            acc[ct] = __builtin_amdgcn_mfma_f32_16x16x32_bf16(a_lo, bh, acc[ct], 0, 0, 0);
            acc[ct] = __builtin_amdgcn_mfma_f32_16x16x32_bf16(a_hi, bh, acc[ct], 0, 0, 0);
        }
    }

    // ---- epilogue: plane-layout xh store + fused a_src/a_dst ----
    int cb = wave;
    float ps[4] = {0.f, 0.f, 0.f, 0.f};
    float pd[4] = {0.f, 0.f, 0.f, 0.f};
#pragma unroll
    for (int ct = 0; ct < 4; ++ct) {
        float as_c = att_s[cb * 64 + ct * 16 + l16] * LOG2E;
        float ad_c = att_d[cb * 64 + ct * 16 + l16] * LOG2E;
        int ch = cb * 64 + ct * 16 + l16;
        int pl = ch >> 5, wc = ch & 31;
#pragma unroll
        for (int r = 0; r < 4; ++r) {
            float v = acc[ct][r];
            int grow = rb + quad * 4 + r;
            if (grow < N)
                xh_pl[((size_t)pl * N + grow) * 32 + wc] = f2bf(v);
            ps[r] += v * as_c;
            pd[r] += v * ad_c;
        }
    }
#pragma unroll
    for (int off = 1; off < 16; off <<= 1) {
#pragma unroll
        for (int r = 0; r < 4; ++r) {
            ps[r] += __shfl_xor(ps[r], off);
            pd[r] += __shfl_xor(pd[r], off);
        }
    }
    if (l16 == 0) {
#pragma unroll
        for (int r = 0; r < 4; ++r) {
            int grow = rb + quad * 4 + r;
            if (grow < N) {
                a_src[(size_t)grow * 4 + cb] = ps[r];
                a_dst[(size_t)grow * 4 + cb] = pd[r];
            }
        }
    }
}

// degree histogram over dst
__global__ __launch_bounds__(256) void deg_count(const int* __restrict__ ei,
                                                 int* __restrict__ deg, int E) {
    int e = blockIdx.x * 256 + threadIdx.x;
    if (e >= E) return;
    atomicAdd(deg + ei[E + e], 1);
}

// ---- device-wide exclusive scan of deg[N] -> rowptr, cursor (2 phases) ----
__global__ __launch_bounds__(256) void scan_part(const int* __restrict__ deg,
                                                 int* __restrict__ part, int N) {
    int t = threadIdx.x;
    int base = blockIdx.x * 1024 + t * 4;
    int s = 0;
    if (base + 4 <= N) {
        int4 v = *(const int4*)(deg + base);
        s = v.x + v.y + v.z + v.w;
    } else {
#pragma unroll
        for (int j = 0; j < 4; ++j)
            if (base + j < N) s += deg[base + j];
    }
#pragma unroll
    for (int off = 1; off < 64; off <<= 1) s += __shfl_xor(s, off);
    __shared__ int ws[4];
    if ((t & 63) == 0) ws[t >> 6] = s;
    __syncthreads();
    if (t == 0) part[blockIdx.x] = ws[0] + ws[1] + ws[2] + ws[3];
}

__global__ __launch_bounds__(256) void scan_final(const int* __restrict__ deg,
                                                  const int* __restrict__ part,
                                                  int* __restrict__ rowptr,
                                                  int* __restrict__ cursor, int N) {
    __shared__ int sm[256];
    __shared__ int wsum[4];
    int t = threadIdx.x;
    int bacc = 0;
    for (int j = t; j < blockIdx.x; j += 256) bacc += part[j];
#pragma unroll
    for (int off = 1; off < 64; off <<= 1) bacc += __shfl_xor(bacc, off);
    if ((t & 63) == 0) wsum[t >> 6] = bacc;

    int base = blockIdx.x * 1024 + t * 4;
    int v0 = 0, v1 = 0, v2 = 0, v3 = 0;
    if (base + 4 <= N) {
        int4 v = *(const int4*)(deg + base);
        v0 = v.x; v1 = v.y; v2 = v.z; v3 = v.w;
    } else {
        if (base + 0 < N) v0 = deg[base + 0];
        if (base + 1 < N) v1 = deg[base + 1];
        if (base + 2 < N) v2 = deg[base + 2];
        if (base + 3 < N) v3 = deg[base + 3];
    }
    int s = v0 + v1 + v2 + v3;
    sm[t] = s;
    __syncthreads();
    for (int off = 1; off < 256; off <<= 1) {
        int tmp = (t >= off) ? sm[t - off] : 0;
        __syncthreads();
        sm[t] += tmp;
        __syncthreads();
    }
    int boff = wsum[0] + wsum[1] + wsum[2] + wsum[3];
    int run = boff + sm[t] - s;   // exclusive prefix for this thread
    int r0 = run, r1 = r0 + v0, r2 = r1 + v1, r3 = r2 + v2;
    if (base + 4 <= N) {
        *(int4*)(rowptr + base) = (int4){r0, r1, r2, r3};
        *(int4*)(cursor + base) = (int4){r0, r1, r2, r3};
    } else {
        if (base + 0 < N) { rowptr[base + 0] = r0; cursor[base + 0] = r0; }
        if (base + 1 < N) { rowptr[base + 1] = r1; cursor[base + 1] = r1; }
        if (base + 2 < N) { rowptr[base + 2] = r2; cursor[base + 2] = r2; }
        if (base + 3 < N) { rowptr[base + 3] = r3; cursor[base + 3] = r3; }
    }
}

// fill CSR: minimal scattered write -- ONE 4-B store per edge.
__global__ __launch_bounds__(256) void fill_csr(const int* __restrict__ ei,
                                                int* __restrict__ cursor,
                                                int* __restrict__ csr_off6, int E) {
    int e = blockIdx.x * 256 + threadIdx.x;
    if (e >= E) return;
    int s = ei[e], d = ei[E + e];
    int slot = atomicAdd(cursor + d, 1);
    csr_off6[slot] = s << 6;   // byte offset into one plane (64 B/row)
}

// softmax stats per (dst, head), WAVE-COOPERATIVE: one 16-lane group per
// (dst, head) pair. Pass A: chunked online max/sum (coalesced 64-B offset
// loads, parallel a_src gathers, width-16 shfl reductions). Pass B: p
// written 16 consecutive floats per store -> full 64-B lines.
// (Round 11's per-thread serial version had WRITE_SIZE 153 MB from
// partial-line writeback: 64 lanes x 64 different lines per store instr.)
__global__ __launch_bounds__(256) void softmax_stats(const int* __restrict__ csr_off6,
                                                     const float* __restrict__ a_src,
                                                     const float* __restrict__ a_dst,
                                                     const int* __restrict__ rowptr,
                                                     const int* __restrict__ deg,
                                                     float* __restrict__ pack,
                                                     float* __restrict__ p_soa,
                                                     int N, int E) {
    int tid = threadIdx.x;
    int grp = tid >> 4;              // 16 groups per block
    int l16 = tid & 15;
    int h   = grp & 3;
    int d   = blockIdx.x * 4 + (grp >> 2);
    if (d >= N) return;
    int start = rowptr[d], cnt = deg[d];
    float adh = a_dst[(size_t)d * 4 + h];
    const int* offs = csr_off6 + start;

    float m = MINIT, l = 0.f;
    for (int base = 0; base < cnt; base += 16) {
        int idx = base + l16;
        bool v = idx < cnt;
        int off = v ? offs[idx] : 0;
        float al = v ? lrelu(a_src[(off >> 4) + h] + adh) : -INFINITY;
        float cm = al;
#pragma unroll
        for (int j = 1; j < 16; j <<= 1) cm = fmaxf(cm, __shfl_xor(cm, j, 16));
        float mn = fmaxf(m, cm);
        float p = fexp2(al - mn);    // pad -> 0
        float cs = p;
#pragma unroll
        for (int j = 1; j < 16; j <<= 1) cs += __shfl_xor(cs, j, 16);
        l = l * fexp2(m - mn) + cs;
        m = mn;
    }
    float inv = 1.f / (l + 1e-16f);
    if (l16 == 0) {
        pack[(size_t)d * 8 + h]     = m;
        pack[(size_t)d * 8 + 4 + h] = inv;
    }
    float* pout = p_soa + (size_t)h * E + start;
    for (int base = 0; base < cnt; base += 16) {
        int idx = base + l16;
        if (idx < cnt) {
            int off = offs[idx];
            float al = lrelu(a_src[(off >> 4) + h] + adh);
            pout[idx] = fexp2(al - m) * inv;
        }
    }
}

// Channel-plane weighted gather, weight-hoisted: per edge-instance just
// {seq off load, seq p load, dwordx2 x-gather, 4 unpack, 4 FMA}.
// 8 lanes/dst x 4ch (dwordx2) -> 8 dsts per wave. plane = blockIdx&7
// (round-robin XCDs -> 3.2 MB plane L2-resident; round 10 measured
// FETCH at the 25.6 MB minimum). Pads: off->0 (hot line), p->0.
__global__ __launch_bounds__(256) void gat_planes(const int* __restrict__ csr_off6,
                                                  const float* __restrict__ p_soa,
                                                  const int* __restrict__ rowptr,
                                                  const int* __restrict__ deg,
                                                  const unsigned short* __restrict__ xh_pl,
                                                  float* __restrict__ out, int N, int E) {
    int tid = threadIdx.x;
    int g   = blockIdx.x & 7;            // plane -> XCD (round-robin heuristic)
    int db  = blockIdx.x >> 3;
    int grp = tid >> 3;                  // 32 dst-groups per block
    int l8  = tid & 7;
    int d   = db * 32 + grp;
    bool dv = d < N;
    int dc  = dv ? d : N - 1;
    int start = rowptr[dc];
    int cnt   = dv ? deg[dc] : 0;
    int h = g >> 1;                      // head covered by this plane

    // wave-max count across the 8 dst-groups in this wave
    int cw = cnt;
    cw = max(cw, __shfl_xor(cw, 8));
    cw = max(cw, __shfl_xor(cw, 16));
    cw = max(cw, __shfl_xor(cw, 32));

    const char* pb = (const char*)xh_pl + (size_t)g * N * 64;
    const float* ph = p_soa + (size_t)h * E + start;
    int lb = l8 * 8;

    float a0 = 0.f, a1 = 0.f, a2 = 0.f, a3 = 0.f;

#define POFF(i) (((i) < cnt) ? csr_off6[start + (i)] : 0)
#define PPV(i)  (((i) < cnt) ? ph[i] : 0.f)

    int   oE  = POFF(0), oO  = POFF(1);
    float pE  = PPV(0),  pO  = PPV(1);
    int   oE1 = POFF(2), oO1 = POFF(3);
    float pE1 = PPV(2),  pO1 = PPV(3);

#pragma unroll 2
    for (int i = 0; i < cw; i += 2) {
        uint2v xE = *(const uint2v*)(pb + (size_t)(unsigned)oE + lb);
        uint2v xO = *(const uint2v*)(pb + (size_t)(unsigned)oO + lb);
        int   oE2 = POFF(i + 4), oO2 = POFF(i + 5);
        float pE2 = PPV(i + 4),  pO2 = PPV(i + 5);

        a0 += pE * blo(xE[0]); a1 += pE * bhi(xE[0]);
        a2 += pE * blo(xE[1]); a3 += pE * bhi(xE[1]);
        a0 += pO * blo(xO[0]); a1 += pO * bhi(xO[0]);
        a2 += pO * blo(xO[1]); a3 += pO * bhi(xO[1]);

        oE = oE1; oO = oO1; oE1 = oE2; oO1 = oO2;
        pE = pE1; pO = pO1; pE1 = pE2; pO1 = pO2;
    }
#undef POFF
#undef PPV

    if (dv) {
        float4v o;
        o[0] = a0; o[1] = a1; o[2] = a2; o[3] = a3;
        *(float4v*)(out + (size_t)d * HC + g * 32 + l8 * 4) = o;
    }
}

// att[e,:] = exp2(lrelu(as+ad) - m[d]) * inv_l[d].
__global__ __launch_bounds__(256) void att_edge(const int* __restrict__ ei,
                                                const float* __restrict__ a_src,
                                                const float* __restrict__ a_dst,
                                                const float* __restrict__ pack,
                                                float* __restrict__ att_out, int E) {
    int e = blockIdx.x * 256 + threadIdx.x;
    if (e >= E) return;
    int s = ei[e], d = ei[E + e];
    float4v as = *(const float4v*)(a_src + (size_t)s * 4);
    float4v ad = *(const float4v*)(a_dst + (size_t)d * 4);
    float4v mm = *(const float4v*)(pack + (size_t)d * 8);
    float4v gg = *(const float4v*)(pack + (size_t)d * 8 + 4);
    float4v o;
#pragma unroll
    for (int h = 0; h < 4; ++h)
        o[h] = fexp2(lrelu(as[h] + ad[h]) - mm[h]) * gg[h];
    *(float4v*)(att_out + (size_t)e * 4) = o;
}

// ---------------- launcher ----------------
extern "C" void kernel_launch(void* const* d_in, const int* in_sizes, int n_in,
                              void* d_out, int out_size, void* d_ws, size_t ws_size,
                              hipStream_t stream) {
    const float* x     = (const float*)d_in[0];  // fp32 [N,256]
    const int*   ei    = (const int*)d_in[1];    // int32 [2,E]
    const float* W     = (const float*)d_in[2];  // fp32 [256,256]
    const float* att_s = (const float*)d_in[3];  // fp32 [4,64]
    const float* att_d = (const float*)d_in[4];  // fp32 [4,64]

    const int N = in_sizes[0] / IN_CH;   // 50000
    const int E = in_sizes[1] / 2;       // 800000

    char* ws = (char*)d_ws;
    size_t off = 0;
    unsigned short* xh_pl = (unsigned short*)(ws + off); off += (size_t)N * HC * 2;
    unsigned short* wt    = (unsigned short*)(ws + off); off += (size_t)IN_CH * HC * 2;
    float* a_src = (float*)(ws + off); off += (size_t)N * H_HEADS * 4;
    float* a_dst = (float*)(ws + off); off += (size_t)N * H_HEADS * 4;
    float* pack  = (float*)(ws + off); off += (size_t)N * 8 * 4;
    int* rowptr  = (int*)(ws + off); off += (size_t)N * 4;
    int* cursor  = (int*)(ws + off); off += (size_t)N * 4;
    int* csr_off6 = (int*)(ws + off); off += (size_t)E * 4;
    float* p_soa = (float*)(ws + off); off += (size_t)E * 4 * 4;  // SoA [4][E]
    int* part    = (int*)(ws + off); off += 1024 * 4;   // scan partials
    size_t zoff = off;  // zero-init region
    int* deg     = (int*)(ws + off); off += (size_t)N * 4;

    float* out     = (float*)d_out;            // [N, 256] fp32
    float* out_att = out + (size_t)N * HC;     // [E, 4]   fp32

    (void)hipMemsetAsync(ws + zoff, 0, off - zoff, stream);  // deg only

    const int NB  = (N + 1023) / 1024;         // scan blocks (49 for N=50000)
    const int NDB = (N + 31) / 32;             // dst-blocks per plane (1563)

    prep_w<<<256, 256, 0, stream>>>(W, wt);
    deg_count<<<(E + 255) / 256, 256, 0, stream>>>(ei, deg, E);
    gemm_xh<<<(N + 15) / 16, 256, 0, stream>>>(x, wt, att_s, att_d,
                                               xh_pl, a_src, a_dst, N);
    scan_part<<<NB, 256, 0, stream>>>(deg, part, N);
    scan_final<<<NB, 256, 0, stream>>>(deg, part, rowptr, cursor, N);
    fill_csr<<<(E + 255) / 256, 256, 0, stream>>>(ei, cursor, csr_off6, E);
    softmax_stats<<<(N + 3) / 4, 256, 0, stream>>>(csr_off6, a_src, a_dst,
                                                   rowptr, deg, pack, p_soa, N, E);
    gat_planes<<<NDB * 8, 256, 0, stream>>>(csr_off6, p_soa, rowptr, deg,
                                            xh_pl, out, N, E);
    att_edge<<<(E + 255) / 256, 256, 0, stream>>>(ei, a_src, a_dst, pack,
                                                  out_att, E);
}